// Round 2
// 546.095 us; speedup vs baseline: 1.0300x; 1.0300x over previous
//
#include <hip/hip_runtime.h>
#include <hip/hip_bf16.h>

typedef __bf16 v8bf __attribute__((ext_vector_type(8)));
typedef unsigned short v8us __attribute__((ext_vector_type(8)));
typedef float  v4f  __attribute__((ext_vector_type(4)));

__device__ __forceinline__ float lrelu02(float x){ return x > 0.f ? x : 0.2f*x; }

__device__ __forceinline__ unsigned short f2bf_rn(float f){
  unsigned int u = __float_as_uint(f);
  u += 0x7fffu + ((u >> 16) & 1u);
  return (unsigned short)(u >> 16);
}
__device__ __forceinline__ float bf2f(unsigned short h){
  return __uint_as_float(((unsigned int)h) << 16);
}

union BF8cast { v8us u; v8bf b; };

// ---------------- CSR build ----------------
__global__ void hist_kernel(const int* __restrict__ dst, int* counts, int E){
  int i = blockIdx.x*blockDim.x + threadIdx.x;
  if (i < E) atomicAdd(&counts[dst[i]], 1);
}

// single block, 1024 threads, n <= 8192
__global__ void scan_kernel(const int* __restrict__ counts, int* ptr, int* cursor, int n){
  __shared__ int sd[1024];
  int t = threadIdx.x;
  int base = t*8;
  int v[8]; int s = 0;
  #pragma unroll
  for (int i = 0; i < 8; ++i){ int x = (base+i < n) ? counts[base+i] : 0; v[i] = x; s += x; }
  sd[t] = s; __syncthreads();
  for (int off = 1; off < 1024; off <<= 1){
    int x = (t >= off) ? sd[t-off] : 0;
    __syncthreads();
    sd[t] += x;
    __syncthreads();
  }
  int run = sd[t] - s;
  #pragma unroll
  for (int i = 0; i < 8; ++i){
    if (base+i < n){ ptr[base+i] = run; cursor[base+i] = run; run += v[i]; }
  }
  if (t == 1023) ptr[n] = run;
}

__global__ void scatter_kernel(const int* __restrict__ src, const int* __restrict__ dst,
                               int* cursor, int* csr_src, int E){
  int i = blockIdx.x*blockDim.x + threadIdx.x;
  if (i < E){
    int p = atomicAdd(&cursor[dst[i]], 1);
    csr_src[p] = src[i];
  }
}

// ---------------- W1 split/transpose + counts zero (fused prep) ----------------
__global__ void prep_kernel(const float* __restrict__ W1,
    unsigned short* wth, unsigned short* wtl, int* counts, int nw, int n){
  int i = blockIdx.x*blockDim.x + threadIdx.x;
  if (i < nw){
    int k = i >> 7, c = i & 127;           // W1 is [512,128] row-major
    float f = W1[i];
    unsigned short h = f2bf_rn(f);
    wth[c*512 + k] = h;                     // transposed: Wt[c][k]
    wtl[c*512 + k] = f2bf_rn(f - bf2f(h));
  } else if (i < nw + n){
    counts[i - nw] = 0;
  }
}

// ---------------- GEMM1: h1 = x @ W1 via bf16-split MFMA, x split in-register,
// alpha1 (h1 @ a_src / a_dst) fused into the epilogue ----------------
// block = 128 threads (2 waves), wave covers 16 rows x 128 cols; grid = M/32
__global__ __launch_bounds__(128) void gemm1_fused(const float* __restrict__ x,
    const unsigned short* __restrict__ wth, const unsigned short* __restrict__ wtl,
    const float* __restrict__ avs, const float* __restrict__ avd,
    float* __restrict__ h1, float* __restrict__ as_out, float* __restrict__ ad_out){
  const int lane = threadIdx.x & 63;
  const int wave = threadIdx.x >> 6;
  const int i0 = blockIdx.x*32 + wave*16;
  const int r = lane & 15, q = lane >> 4;
  const float* xr = x + (size_t)(i0 + r)*512;
  v4f acc[8];
  #pragma unroll
  for (int c = 0; c < 8; ++c) acc[c] = (v4f){0.f,0.f,0.f,0.f};
  for (int kt = 0; kt < 16; ++kt){
    int k = kt*32 + q*8;
    v4f xa = *reinterpret_cast<const v4f*>(xr + k);
    v4f xb = *reinterpret_cast<const v4f*>(xr + k + 4);
    v8us ahu, alu;
    #pragma unroll
    for (int j = 0; j < 8; ++j){
      float f = (j < 4) ? xa[j] : xb[j-4];
      unsigned short hh = f2bf_rn(f);
      ahu[j] = hh;
      alu[j] = f2bf_rn(f - bf2f(hh));
    }
    BF8cast ch; ch.u = ahu;
    BF8cast cl; cl.u = alu;
    v8bf ah = ch.b, al = cl.b;
    #pragma unroll
    for (int ct = 0; ct < 8; ++ct){
      v8bf bh = *reinterpret_cast<const v8bf*>(wth + (size_t)(ct*16 + r)*512 + k);
      v8bf bl = *reinterpret_cast<const v8bf*>(wtl + (size_t)(ct*16 + r)*512 + k);
      acc[ct] = __builtin_amdgcn_mfma_f32_16x16x32_bf16(ah, bh, acc[ct], 0,0,0);
      acc[ct] = __builtin_amdgcn_mfma_f32_16x16x32_bf16(al, bh, acc[ct], 0,0,0);
      acc[ct] = __builtin_amdgcn_mfma_f32_16x16x32_bf16(ah, bl, acc[ct], 0,0,0);
    }
  }
  // C/D: col = ct*16 + (lane&15), row = i0 + q*4 + t
  #pragma unroll
  for (int ct = 0; ct < 8; ++ct)
    #pragma unroll
    for (int t = 0; t < 4; ++t)
      h1[(size_t)(i0 + q*4 + t)*128 + ct*16 + r] = acc[ct][t];
  // fused alpha: row dot a_src / a_dst. Row (q*4+t) lives across the 16 r-lanes.
  float sa[4] = {0.f,0.f,0.f,0.f}, da[4] = {0.f,0.f,0.f,0.f};
  #pragma unroll
  for (int ct = 0; ct < 8; ++ct){
    float ws = avs[ct*16 + r], wd = avd[ct*16 + r];
    #pragma unroll
    for (int t = 0; t < 4; ++t){ sa[t] += acc[ct][t]*ws; da[t] += acc[ct][t]*wd; }
  }
  #pragma unroll
  for (int off = 1; off < 16; off <<= 1){
    #pragma unroll
    for (int t = 0; t < 4; ++t){
      sa[t] += __shfl_xor(sa[t], off);
      da[t] += __shfl_xor(da[t], off);
    }
  }
  if (r == 0){
    #pragma unroll
    for (int t = 0; t < 4; ++t){
      as_out[i0 + q*4 + t] = sa[t];
      ad_out[i0 + q*4 + t] = da[t];
    }
  }
}

// ---------------- GAT layer 1: softmax + aggregate (wave per node, 2 edges/iter) ----------------
__global__ void gat_agg1(const float* __restrict__ h, const float* __restrict__ as,
                         const float* __restrict__ ad, const int* __restrict__ ptr,
                         const int* __restrict__ csr_src, const float* __restrict__ bias,
                         float* __restrict__ out, int n){
  const int F = 128;
  int wid = (blockIdx.x*blockDim.x + threadIdx.x) >> 6;
  int lane = threadIdx.x & 63;
  if (wid >= n) return;
  const int v = wid;
  const int beg = ptr[v], end = ptr[v+1];
  const float adv = ad[v];
  const float asv = as[v];
  float m = lrelu02(asv + adv);
  for (int j = beg + lane; j < end; j += 64)
    m = fmaxf(m, lrelu02(as[csr_src[j]] + adv));
  for (int o = 32; o; o >>= 1) m = fmaxf(m, __shfl_xor(m, o));
  const int half = lane >> 5, l32 = lane & 31;
  v4f acc = (v4f){0.f,0.f,0.f,0.f};
  float wself = __expf(lrelu02(asv + adv) - m);
  float ssum = (lane == 0) ? wself : 0.f;
  if (half == 0){
    v4f hv = *reinterpret_cast<const v4f*>(h + (size_t)v*F + l32*4);
    acc += hv * wself;
  }
  for (int b0 = beg; b0 < end; b0 += 64){
    int j = b0 + lane;
    float wv = 0.f; int sv = 0;
    if (j < end){
      sv = csr_src[j];
      wv = __expf(lrelu02(as[sv] + adv) - m);
      ssum += wv;
    }
    int cnt = min(64, end - b0);
    for (int t = 0; t < cnt; t += 2){
      int idx = t + half;
      float wt = __shfl(wv, idx);
      int   st = __shfl(sv, idx);
      if (idx >= cnt){ wt = 0.f; st = v; }
      v4f hv = *reinterpret_cast<const v4f*>(h + (size_t)st*F + l32*4);
      acc += hv * wt;
    }
  }
  for (int o = 32; o; o >>= 1) ssum += __shfl_xor(ssum, o);
  #pragma unroll
  for (int c = 0; c < 4; ++c) acc[c] += __shfl_xor(acc[c], 32);
  if (half == 0){
    float inv = 1.f / ssum;
    v4f bv = *reinterpret_cast<const v4f*>(bias + l32*4);
    v4f rr;
    #pragma unroll
    for (int c = 0; c < 4; ++c){
      float r0 = acc[c]*inv + bv[c];
      rr[c] = r0 > 0.f ? r0 : __expf(r0) - 1.f;   // ELU
    }
    *reinterpret_cast<v4f*>(out + (size_t)v*F + l32*4) = rr;
  }
}

// ---------------- fp32 tiled GEMM (layer-2 feature transform) + fused alpha2 ----------------
template<int BM,int BN,int BK,int TM,int TN>
__global__ __launch_bounds__(256) void gemm2_fused(const float* __restrict__ A,
    const float* __restrict__ B, float* __restrict__ C, int M, int N, int K,
    const float* __restrict__ avs, const float* __restrict__ avd,
    float* __restrict__ as_out, float* __restrict__ ad_out){
  __shared__ float As[BK][BM+1];
  __shared__ float Bs[BK][BN+1];
  __shared__ float reds[BM][17];
  __shared__ float redd[BM][17];
  const int tid = threadIdx.x;
  const int tx = tid % (BN/TN);
  const int ty = tid / (BN/TN);
  const int brow = blockIdx.y*BM;
  const int bcol = blockIdx.x*BN;
  float acc[TM][TN] = {};
  for (int k0 = 0; k0 < K; k0 += BK){
    for (int i = tid; i < BM*BK; i += 256){
      int m = i / BK, kk = i % BK;
      As[kk][m] = A[(size_t)(brow+m)*K + k0 + kk];
    }
    for (int i = tid; i < BK*BN; i += 256){
      int kk = i / BN, nn = i % BN;
      Bs[kk][nn] = B[(size_t)(k0+kk)*N + bcol + nn];
    }
    __syncthreads();
    #pragma unroll
    for (int kk = 0; kk < BK; ++kk){
      float a[TM], b[TN];
      #pragma unroll
      for (int m = 0; m < TM; ++m) a[m] = As[kk][ty*TM+m];
      #pragma unroll
      for (int n = 0; n < TN; ++n) b[n] = Bs[kk][tx*TN+n];
      #pragma unroll
      for (int m = 0; m < TM; ++m)
        #pragma unroll
        for (int n = 0; n < TN; ++n) acc[m][n] += a[m]*b[n];
    }
    __syncthreads();
  }
  float ps[TM] = {}, pd[TM] = {};
  #pragma unroll
  for (int m = 0; m < TM; ++m){
    #pragma unroll
    for (int n = 0; n < TN; ++n){
      float c = acc[m][n];
      C[(size_t)(brow+ty*TM+m)*N + bcol+tx*TN+n] = c;
      float s = avs[bcol+tx*TN+n], d = avd[bcol+tx*TN+n];
      ps[m] += c*s; pd[m] += c*d;
    }
  }
  #pragma unroll
  for (int m = 0; m < TM; ++m){
    reds[ty*TM+m][tx] = ps[m];
    redd[ty*TM+m][tx] = pd[m];
  }
  __syncthreads();
  if (tid < BM){
    float s = 0.f, d = 0.f;
    #pragma unroll
    for (int k = 0; k < BN/TN; ++k){ s += reds[tid][k]; d += redd[tid][k]; }
    as_out[brow + tid] = s;
    ad_out[brow + tid] = d;
  }
}

// ---------------- GAT layer 2 + z-split + Student-t q (fused, 4 edges/iter) ----------------
__global__ void gat_agg2_fused(const float* __restrict__ h, const float* __restrict__ as,
                               const float* __restrict__ ad, const int* __restrict__ ptr,
                               const int* __restrict__ csr_src, const float* __restrict__ bias,
                               const float* __restrict__ centers,
                               float* __restrict__ z_out, unsigned short* __restrict__ zhi,
                               unsigned short* __restrict__ zlo, float* __restrict__ qout,
                               int n, int K){
  const int F = 64;
  int wid = (blockIdx.x*blockDim.x + threadIdx.x) >> 6;
  int lane = threadIdx.x & 63;
  if (wid >= n) return;
  const int v = wid;
  const int beg = ptr[v], end = ptr[v+1];
  const float adv = ad[v];
  const float asv = as[v];
  float m = lrelu02(asv + adv);
  for (int j = beg + lane; j < end; j += 64)
    m = fmaxf(m, lrelu02(as[csr_src[j]] + adv));
  for (int o = 32; o; o >>= 1) m = fmaxf(m, __shfl_xor(m, o));
  const int qr = lane >> 4, l16 = lane & 15;
  v4f acc = (v4f){0.f,0.f,0.f,0.f};
  float wself = __expf(lrelu02(asv + adv) - m);
  float ssum = (lane == 0) ? wself : 0.f;
  if (qr == 0){
    v4f hv = *reinterpret_cast<const v4f*>(h + (size_t)v*F + l16*4);
    acc += hv * wself;
  }
  for (int b0 = beg; b0 < end; b0 += 64){
    int j = b0 + lane;
    float wv = 0.f; int sv = 0;
    if (j < end){
      sv = csr_src[j];
      wv = __expf(lrelu02(as[sv] + adv) - m);
      ssum += wv;
    }
    int cnt = min(64, end - b0);
    for (int t = 0; t < cnt; t += 4){
      int idx = t + qr;
      float wt = __shfl(wv, idx);
      int   st = __shfl(sv, idx);
      if (idx >= cnt){ wt = 0.f; st = v; }
      v4f hv = *reinterpret_cast<const v4f*>(h + (size_t)st*F + l16*4);
      acc += hv * wt;
    }
  }
  for (int o = 32; o; o >>= 1) ssum += __shfl_xor(ssum, o);
  // combine the 4 quarter-wave partials (all quarters hold cols l16*4..+3)
  #pragma unroll
  for (int c = 0; c < 4; ++c){
    acc[c] += __shfl_xor(acc[c], 16);
    acc[c] += __shfl_xor(acc[c], 32);
  }
  // redistribute: lane wants col=lane = component (lane&3) of lane (lane>>2)
  int srcLane = lane >> 2;
  float c0 = __shfl(acc[0], srcLane);
  float c1 = __shfl(acc[1], srcLane);
  float c2 = __shfl(acc[2], srcLane);
  float c3 = __shfl(acc[3], srcLane);
  int sel = lane & 3;
  float av = sel == 0 ? c0 : sel == 1 ? c1 : sel == 2 ? c2 : c3;
  float r0 = av / ssum + bias[lane];     // z row, one float per lane
  z_out[(size_t)v*F + lane] = r0;
  unsigned short hh = f2bf_rn(r0);
  zhi[(size_t)v*F + lane] = hh;
  zlo[(size_t)v*F + lane] = f2bf_rn(r0 - bf2f(hh));
  // Student-t q
  float myq = 0.f, tot = 0.f;
  for (int k = 0; k < K; ++k){
    float d = r0 - centers[k*F + lane];
    float d2 = d*d;
    for (int o = 32; o; o >>= 1) d2 += __shfl_xor(d2, o);
    float qq = 1.f / (1.f + d2);
    if (lane == k) myq = qq;
    tot += qq;
  }
  if (lane < K) qout[(size_t)v*K + lane] = myq / tot;
}

// ---------------- A_pred = sigmoid(z z^T) via bf16-split MFMA ----------------
__device__ __forceinline__ v8bf ldz(const unsigned short* z, int node, int k){
  return *reinterpret_cast<const v8bf*>(z + ((size_t)node << 6) + k);
}

__global__ __launch_bounds__(256) void apred_kernel(const unsigned short* __restrict__ zhi,
    const unsigned short* __restrict__ zlo, float* __restrict__ out, int N){
  __shared__ float tile[4][16][68];        // per-wave private 16x64 (+4 pad)
  const int lane = threadIdx.x & 63;
  const int wave = threadIdx.x >> 6;
  const int i0 = blockIdx.y*64 + wave*16;
  const int j0 = blockIdx.x*64;
  const int r = lane & 15, q = lane >> 4;
  const int arow = i0 + r;
  v8bf ahi0 = ldz(zhi, arow,      q*8);
  v8bf ahi1 = ldz(zhi, arow, 32 + q*8);
  v8bf alo0 = ldz(zlo, arow,      q*8);
  v8bf alo1 = ldz(zlo, arow, 32 + q*8);
  #pragma unroll
  for (int c = 0; c < 4; ++c){
    int brow = j0 + c*16 + r;
    v8bf bhi0 = ldz(zhi, brow,      q*8);
    v8bf bhi1 = ldz(zhi, brow, 32 + q*8);
    v8bf blo0 = ldz(zlo, brow,      q*8);
    v8bf blo1 = ldz(zlo, brow, 32 + q*8);
    v4f acc = {0.f,0.f,0.f,0.f};
    acc = __builtin_amdgcn_mfma_f32_16x16x32_bf16(ahi0, bhi0, acc, 0,0,0);
    acc = __builtin_amdgcn_mfma_f32_16x16x32_bf16(ahi1, bhi1, acc, 0,0,0);
    acc = __builtin_amdgcn_mfma_f32_16x16x32_bf16(ahi0, blo0, acc, 0,0,0);
    acc = __builtin_amdgcn_mfma_f32_16x16x32_bf16(ahi1, blo1, acc, 0,0,0);
    acc = __builtin_amdgcn_mfma_f32_16x16x32_bf16(alo0, bhi0, acc, 0,0,0);
    acc = __builtin_amdgcn_mfma_f32_16x16x32_bf16(alo1, bhi1, acc, 0,0,0);
    // C/D: col = lane&15, row = q*4 + t  -> sigmoid -> LDS (wave-private, no barrier)
    #pragma unroll
    for (int t = 0; t < 4; ++t){
      float e = __expf(-acc[t]);
      tile[wave][q*4 + t][c*16 + r] = __builtin_amdgcn_rcpf(1.f + e);
    }
  }
  // store: each instr writes 4 full 256B-contiguous rows (16 lanes x float4 per row)
  #pragma unroll
  for (int t = 0; t < 4; ++t){
    int row = t*4 + (lane >> 4);
    int col = (lane & 15)*4;
    v4f vv = *reinterpret_cast<v4f*>(&tile[wave][row][col]);
    __builtin_nontemporal_store(vv, reinterpret_cast<v4f*>(out + (size_t)(i0 + row)*N + j0 + col));
  }
}

// ---------------- launch ----------------
extern "C" void kernel_launch(void* const* d_in, const int* in_sizes, int n_in,
                              void* d_out, int out_size, void* d_ws, size_t ws_size,
                              hipStream_t stream) {
  const float* x      = (const float*)d_in[0];
  const int*   ei     = (const int*)  d_in[1];
  const float* W1     = (const float*)d_in[2];
  const float* a_src1 = (const float*)d_in[3];
  const float* a_dst1 = (const float*)d_in[4];
  const float* b1     = (const float*)d_in[5];
  const float* W2     = (const float*)d_in[6];
  const float* a_src2 = (const float*)d_in[7];
  const float* a_dst2 = (const float*)d_in[8];
  const float* b2     = (const float*)d_in[9];
  const float* cent   = (const float*)d_in[10];

  const int H   = in_sizes[3];          // 128
  const int OUTF= in_sizes[7];          // 64
  const int INF = in_sizes[2] / H;      // 512
  const int N   = in_sizes[0] / INF;    // 8192
  const int E   = in_sizes[1] / 2;      // 262144
  const int K   = in_sizes[10] / OUTF;  // 16

  const int* e_src = ei;
  const int* e_dst = ei + E;

  char* wsp = (char*)d_ws;
  auto alloc = [&](size_t b)->void*{ void* p = (void*)wsp; wsp += (b + 255) & ~(size_t)255; return p; };
  int* counts   = (int*)alloc((size_t)N*4);
  int* ptr      = (int*)alloc((size_t)(N+1)*4);
  int* cursor   = (int*)alloc((size_t)N*4);
  int* csr_src  = (int*)alloc((size_t)E*4);
  float* as1    = (float*)alloc((size_t)N*4);
  float* ad1    = (float*)alloc((size_t)N*4);
  float* as2    = (float*)alloc((size_t)N*4);
  float* ad2    = (float*)alloc((size_t)N*4);
  unsigned short* zhi = (unsigned short*)alloc((size_t)N*OUTF*2);
  unsigned short* zlo = (unsigned short*)alloc((size_t)N*OUTF*2);
  unsigned short* wth = (unsigned short*)alloc((size_t)INF*H*2);
  unsigned short* wtl = (unsigned short*)alloc((size_t)INF*H*2);

  float* out_f  = (float*)d_out;
  float* z_out  = out_f;                              // [N, 64]
  float* ap_out = out_f + (size_t)N*OUTF;             // [N, N]
  float* q_out  = ap_out + (size_t)N*N;               // [N, K]
  float* h1  = ap_out;                                // scratch (dead before apred)
  float* h2  = h1 + (size_t)N*H;
  float* h2w = h2 + (size_t)N*H;

  const int wavesPerGrid = (N*64 + 255)/256;
  const int nw = INF*H;

  prep_kernel<<<(nw + N + 255)/256, 256, 0, stream>>>(W1, wth, wtl, counts, nw, N);
  hist_kernel<<<(E+255)/256, 256, 0, stream>>>(e_dst, counts, E);
  scan_kernel<<<1, 1024, 0, stream>>>(counts, ptr, cursor, N);
  scatter_kernel<<<(E+255)/256, 256, 0, stream>>>(e_src, e_dst, cursor, csr_src, E);
  gemm1_fused<<<N/32, 128, 0, stream>>>(x, wth, wtl, a_src1, a_dst1, h1, as1, ad1);
  gat_agg1<<<wavesPerGrid, 256, 0, stream>>>(h1, as1, ad1, ptr, csr_src, b1, h2, N);
  gemm2_fused<64,64,16,4,4><<<dim3(OUTF/64, N/64), 256, 0, stream>>>(h2, W2, h2w, N, OUTF, H,
                                                                     a_src2, a_dst2, as2, ad2);
  gat_agg2_fused<<<wavesPerGrid, 256, 0, stream>>>(h2w, as2, ad2, ptr, csr_src, b2, cent,
                                                   z_out, zhi, zlo, q_out, N, K);
  apred_kernel<<<dim3(N/64, N/64), 256, 0, stream>>>(zhi, zlo, ap_out, N);
}

// Round 3
// 528.223 us; speedup vs baseline: 1.0648x; 1.0338x over previous
//
#include <hip/hip_runtime.h>
#include <hip/hip_bf16.h>

typedef __bf16 v8bf __attribute__((ext_vector_type(8)));
typedef unsigned short v8us __attribute__((ext_vector_type(8)));
typedef float  v4f  __attribute__((ext_vector_type(4)));

__device__ __forceinline__ float lrelu02(float x){ return x > 0.f ? x : 0.2f*x; }

__device__ __forceinline__ unsigned short f2bf_rn(float f){
  unsigned int u = __float_as_uint(f);
  u += 0x7fffu + ((u >> 16) & 1u);
  return (unsigned short)(u >> 16);
}
__device__ __forceinline__ float bf2f(unsigned short h){
  return __uint_as_float(((unsigned int)h) << 16);
}

union BF8cast { v8us u; v8bf b; };

// ---------------- CSR build ----------------
__global__ void hist_kernel(const int* __restrict__ dst, int* counts, int E){
  int i = blockIdx.x*blockDim.x + threadIdx.x;
  if (i < E) atomicAdd(&counts[dst[i]], 1);
}

// single block, 1024 threads, n <= 8192
__global__ void scan_kernel(const int* __restrict__ counts, int* ptr, int* cursor, int n){
  __shared__ int sd[1024];
  int t = threadIdx.x;
  int base = t*8;
  int v[8]; int s = 0;
  #pragma unroll
  for (int i = 0; i < 8; ++i){ int x = (base+i < n) ? counts[base+i] : 0; v[i] = x; s += x; }
  sd[t] = s; __syncthreads();
  for (int off = 1; off < 1024; off <<= 1){
    int x = (t >= off) ? sd[t-off] : 0;
    __syncthreads();
    sd[t] += x;
    __syncthreads();
  }
  int run = sd[t] - s;
  #pragma unroll
  for (int i = 0; i < 8; ++i){
    if (base+i < n){ ptr[base+i] = run; cursor[base+i] = run; run += v[i]; }
  }
  if (t == 1023) ptr[n] = run;
}

__global__ void scatter_kernel(const int* __restrict__ src, const int* __restrict__ dst,
                               int* cursor, int* csr_src, int E){
  int i = blockIdx.x*blockDim.x + threadIdx.x;
  if (i < E){
    int p = atomicAdd(&cursor[dst[i]], 1);
    csr_src[p] = src[i];
  }
}

// ---------------- W1 split/transpose + counts zero (fused prep) ----------------
__global__ void prep_kernel(const float* __restrict__ W1,
    unsigned short* wth, unsigned short* wtl, int* counts, int nw, int n){
  int i = blockIdx.x*blockDim.x + threadIdx.x;
  if (i < nw){
    int k = i >> 7, c = i & 127;           // W1 is [512,128] row-major
    float f = W1[i];
    unsigned short h = f2bf_rn(f);
    wth[c*512 + k] = h;                     // transposed: Wt[c][k]
    wtl[c*512 + k] = f2bf_rn(f - bf2f(h));
  } else if (i < nw + n){
    counts[i - nw] = 0;
  }
}

// ---------------- GEMM1: h1 = x @ W1 via bf16-split MFMA, x split in-register,
// alpha1 (h1 @ a_src / a_dst) fused into the epilogue ----------------
// block = 128 threads (2 waves), wave covers 16 rows x 128 cols; grid = M/32
__global__ __launch_bounds__(128) void gemm1_fused(const float* __restrict__ x,
    const unsigned short* __restrict__ wth, const unsigned short* __restrict__ wtl,
    const float* __restrict__ avs, const float* __restrict__ avd,
    float* __restrict__ h1, float* __restrict__ as_out, float* __restrict__ ad_out){
  const int lane = threadIdx.x & 63;
  const int wave = threadIdx.x >> 6;
  const int i0 = blockIdx.x*32 + wave*16;
  const int r = lane & 15, q = lane >> 4;
  const float* xr = x + (size_t)(i0 + r)*512;
  v4f acc[8];
  #pragma unroll
  for (int c = 0; c < 8; ++c) acc[c] = (v4f){0.f,0.f,0.f,0.f};
  for (int kt = 0; kt < 16; ++kt){
    int k = kt*32 + q*8;
    v4f xa = *reinterpret_cast<const v4f*>(xr + k);
    v4f xb = *reinterpret_cast<const v4f*>(xr + k + 4);
    v8us ahu, alu;
    #pragma unroll
    for (int j = 0; j < 8; ++j){
      float f = (j < 4) ? xa[j] : xb[j-4];
      unsigned short hh = f2bf_rn(f);
      ahu[j] = hh;
      alu[j] = f2bf_rn(f - bf2f(hh));
    }
    BF8cast ch; ch.u = ahu;
    BF8cast cl; cl.u = alu;
    v8bf ah = ch.b, al = cl.b;
    #pragma unroll
    for (int ct = 0; ct < 8; ++ct){
      v8bf bh = *reinterpret_cast<const v8bf*>(wth + (size_t)(ct*16 + r)*512 + k);
      v8bf bl = *reinterpret_cast<const v8bf*>(wtl + (size_t)(ct*16 + r)*512 + k);
      acc[ct] = __builtin_amdgcn_mfma_f32_16x16x32_bf16(ah, bh, acc[ct], 0,0,0);
      acc[ct] = __builtin_amdgcn_mfma_f32_16x16x32_bf16(al, bh, acc[ct], 0,0,0);
      acc[ct] = __builtin_amdgcn_mfma_f32_16x16x32_bf16(ah, bl, acc[ct], 0,0,0);
    }
  }
  // C/D: col = ct*16 + (lane&15), row = i0 + q*4 + t
  #pragma unroll
  for (int ct = 0; ct < 8; ++ct)
    #pragma unroll
    for (int t = 0; t < 4; ++t)
      h1[(size_t)(i0 + q*4 + t)*128 + ct*16 + r] = acc[ct][t];
  // fused alpha: row dot a_src / a_dst. Row (q*4+t) lives across the 16 r-lanes.
  float sa[4] = {0.f,0.f,0.f,0.f}, da[4] = {0.f,0.f,0.f,0.f};
  #pragma unroll
  for (int ct = 0; ct < 8; ++ct){
    float ws = avs[ct*16 + r], wd = avd[ct*16 + r];
    #pragma unroll
    for (int t = 0; t < 4; ++t){ sa[t] += acc[ct][t]*ws; da[t] += acc[ct][t]*wd; }
  }
  #pragma unroll
  for (int off = 1; off < 16; off <<= 1){
    #pragma unroll
    for (int t = 0; t < 4; ++t){
      sa[t] += __shfl_xor(sa[t], off);
      da[t] += __shfl_xor(da[t], off);
    }
  }
  if (r == 0){
    #pragma unroll
    for (int t = 0; t < 4; ++t){
      as_out[i0 + q*4 + t] = sa[t];
      ad_out[i0 + q*4 + t] = da[t];
    }
  }
}

// ---------------- GAT layer 1: softmax + aggregate (wave per node, 2 edges/iter)
// first 64 edges' src-ids and logits cached in registers from the max pass ----------------
__global__ void gat_agg1(const float* __restrict__ h, const float* __restrict__ as,
                         const float* __restrict__ ad, const int* __restrict__ ptr,
                         const int* __restrict__ csr_src, const float* __restrict__ bias,
                         float* __restrict__ out, int n){
  const int F = 128;
  int wid = (blockIdx.x*blockDim.x + threadIdx.x) >> 6;
  int lane = threadIdx.x & 63;
  if (wid >= n) return;
  const int v = wid;
  const int beg = ptr[v], end = ptr[v+1];
  const int deg = end - beg;
  const float adv = ad[v];
  const float asv = as[v];
  const float eself = lrelu02(asv + adv);
  // cached first chunk (covers deg<=64, which is ~all nodes at mean degree 32)
  int sv0 = v; float e0 = -3.4e38f;
  if (lane < deg){ sv0 = csr_src[beg + lane]; e0 = lrelu02(as[sv0] + adv); }
  float m = fmaxf(eself, e0);
  for (int j = beg + 64 + lane; j < end; j += 64)
    m = fmaxf(m, lrelu02(as[csr_src[j]] + adv));
  for (int o = 32; o; o >>= 1) m = fmaxf(m, __shfl_xor(m, o));
  float wv0 = (lane < deg) ? __expf(e0 - m) : 0.f;
  float wself = __expf(eself - m);
  float ssum = wv0 + ((lane == 0) ? wself : 0.f);
  const int half = lane >> 5, l32 = lane & 31;
  v4f acc = (v4f){0.f,0.f,0.f,0.f};
  if (half == 0){
    v4f hv = *reinterpret_cast<const v4f*>(h + (size_t)v*F + l32*4);
    acc += hv * wself;
  }
  // first chunk aggregate from register cache
  {
    int cnt = min(64, deg);
    for (int t = 0; t < cnt; t += 2){
      int idx = t + half;
      float wt = __shfl(wv0, idx);
      int   st = __shfl(sv0, idx);
      if (idx >= cnt){ wt = 0.f; st = v; }
      v4f hv = *reinterpret_cast<const v4f*>(h + (size_t)st*F + l32*4);
      acc += hv * wt;
    }
  }
  // tail chunks (deg > 64: rare)
  for (int b0 = beg + 64; b0 < end; b0 += 64){
    int j = b0 + lane;
    float wv = 0.f; int sv = v;
    if (j < end){
      sv = csr_src[j];
      wv = __expf(lrelu02(as[sv] + adv) - m);
      ssum += wv;
    }
    int cnt = min(64, end - b0);
    for (int t = 0; t < cnt; t += 2){
      int idx = t + half;
      float wt = __shfl(wv, idx);
      int   st = __shfl(sv, idx);
      if (idx >= cnt){ wt = 0.f; st = v; }
      v4f hv = *reinterpret_cast<const v4f*>(h + (size_t)st*F + l32*4);
      acc += hv * wt;
    }
  }
  for (int o = 32; o; o >>= 1) ssum += __shfl_xor(ssum, o);
  #pragma unroll
  for (int c = 0; c < 4; ++c) acc[c] += __shfl_xor(acc[c], 32);
  if (half == 0){
    float inv = 1.f / ssum;
    v4f bv = *reinterpret_cast<const v4f*>(bias + l32*4);
    v4f rr;
    #pragma unroll
    for (int c = 0; c < 4; ++c){
      float r0 = acc[c]*inv + bv[c];
      rr[c] = r0 > 0.f ? r0 : __expf(r0) - 1.f;   // ELU
    }
    *reinterpret_cast<v4f*>(out + (size_t)v*F + l32*4) = rr;
  }
}

// ---------------- fp32 tiled GEMM (layer-2 feature transform) + fused alpha2 ----------------
template<int BM,int BN,int BK,int TM,int TN>
__global__ __launch_bounds__(256) void gemm2_fused(const float* __restrict__ A,
    const float* __restrict__ B, float* __restrict__ C, int M, int N, int K,
    const float* __restrict__ avs, const float* __restrict__ avd,
    float* __restrict__ as_out, float* __restrict__ ad_out){
  __shared__ float As[BK][BM+1];
  __shared__ float Bs[BK][BN+1];
  __shared__ float reds[BM][17];
  __shared__ float redd[BM][17];
  const int tid = threadIdx.x;
  const int tx = tid % (BN/TN);
  const int ty = tid / (BN/TN);
  const int brow = blockIdx.y*BM;
  const int bcol = blockIdx.x*BN;
  float acc[TM][TN] = {};
  for (int k0 = 0; k0 < K; k0 += BK){
    for (int i = tid; i < BM*BK; i += 256){
      int m = i / BK, kk = i % BK;
      As[kk][m] = A[(size_t)(brow+m)*K + k0 + kk];
    }
    for (int i = tid; i < BK*BN; i += 256){
      int kk = i / BN, nn = i % BN;
      Bs[kk][nn] = B[(size_t)(k0+kk)*N + bcol + nn];
    }
    __syncthreads();
    #pragma unroll
    for (int kk = 0; kk < BK; ++kk){
      float a[TM], b[TN];
      #pragma unroll
      for (int m = 0; m < TM; ++m) a[m] = As[kk][ty*TM+m];
      #pragma unroll
      for (int n = 0; n < TN; ++n) b[n] = Bs[kk][tx*TN+n];
      #pragma unroll
      for (int m = 0; m < TM; ++m)
        #pragma unroll
        for (int n = 0; n < TN; ++n) acc[m][n] += a[m]*b[n];
    }
    __syncthreads();
  }
  float ps[TM] = {}, pd[TM] = {};
  #pragma unroll
  for (int m = 0; m < TM; ++m){
    #pragma unroll
    for (int n = 0; n < TN; ++n){
      float c = acc[m][n];
      C[(size_t)(brow+ty*TM+m)*N + bcol+tx*TN+n] = c;
      float s = avs[bcol+tx*TN+n], d = avd[bcol+tx*TN+n];
      ps[m] += c*s; pd[m] += c*d;
    }
  }
  #pragma unroll
  for (int m = 0; m < TM; ++m){
    reds[ty*TM+m][tx] = ps[m];
    redd[ty*TM+m][tx] = pd[m];
  }
  __syncthreads();
  if (tid < BM){
    float s = 0.f, d = 0.f;
    #pragma unroll
    for (int k = 0; k < BN/TN; ++k){ s += reds[tid][k]; d += redd[tid][k]; }
    as_out[brow + tid] = s;
    ad_out[brow + tid] = d;
  }
}

// ---------------- GAT layer 2 + z-split + Student-t q (fused, 4 edges/iter)
// first 64 edges cached in registers from the max pass ----------------
__global__ void gat_agg2_fused(const float* __restrict__ h, const float* __restrict__ as,
                               const float* __restrict__ ad, const int* __restrict__ ptr,
                               const int* __restrict__ csr_src, const float* __restrict__ bias,
                               const float* __restrict__ centers,
                               float* __restrict__ z_out, unsigned short* __restrict__ zhi,
                               unsigned short* __restrict__ zlo, float* __restrict__ qout,
                               int n, int K){
  const int F = 64;
  int wid = (blockIdx.x*blockDim.x + threadIdx.x) >> 6;
  int lane = threadIdx.x & 63;
  if (wid >= n) return;
  const int v = wid;
  const int beg = ptr[v], end = ptr[v+1];
  const int deg = end - beg;
  const float adv = ad[v];
  const float asv = as[v];
  const float eself = lrelu02(asv + adv);
  int sv0 = v; float e0 = -3.4e38f;
  if (lane < deg){ sv0 = csr_src[beg + lane]; e0 = lrelu02(as[sv0] + adv); }
  float m = fmaxf(eself, e0);
  for (int j = beg + 64 + lane; j < end; j += 64)
    m = fmaxf(m, lrelu02(as[csr_src[j]] + adv));
  for (int o = 32; o; o >>= 1) m = fmaxf(m, __shfl_xor(m, o));
  float wv0 = (lane < deg) ? __expf(e0 - m) : 0.f;
  float wself = __expf(eself - m);
  float ssum = wv0 + ((lane == 0) ? wself : 0.f);
  const int qr = lane >> 4, l16 = lane & 15;
  v4f acc = (v4f){0.f,0.f,0.f,0.f};
  if (qr == 0){
    v4f hv = *reinterpret_cast<const v4f*>(h + (size_t)v*F + l16*4);
    acc += hv * wself;
  }
  {
    int cnt = min(64, deg);
    for (int t = 0; t < cnt; t += 4){
      int idx = t + qr;
      float wt = __shfl(wv0, idx);
      int   st = __shfl(sv0, idx);
      if (idx >= cnt){ wt = 0.f; st = v; }
      v4f hv = *reinterpret_cast<const v4f*>(h + (size_t)st*F + l16*4);
      acc += hv * wt;
    }
  }
  for (int b0 = beg + 64; b0 < end; b0 += 64){
    int j = b0 + lane;
    float wv = 0.f; int sv = v;
    if (j < end){
      sv = csr_src[j];
      wv = __expf(lrelu02(as[sv] + adv) - m);
      ssum += wv;
    }
    int cnt = min(64, end - b0);
    for (int t = 0; t < cnt; t += 4){
      int idx = t + qr;
      float wt = __shfl(wv, idx);
      int   st = __shfl(sv, idx);
      if (idx >= cnt){ wt = 0.f; st = v; }
      v4f hv = *reinterpret_cast<const v4f*>(h + (size_t)st*F + l16*4);
      acc += hv * wt;
    }
  }
  for (int o = 32; o; o >>= 1) ssum += __shfl_xor(ssum, o);
  // combine the 4 quarter-wave partials (all quarters hold cols l16*4..+3)
  #pragma unroll
  for (int c = 0; c < 4; ++c){
    acc[c] += __shfl_xor(acc[c], 16);
    acc[c] += __shfl_xor(acc[c], 32);
  }
  // redistribute: lane wants col=lane = component (lane&3) of lane (lane>>2)
  int srcLane = lane >> 2;
  float c0 = __shfl(acc[0], srcLane);
  float c1 = __shfl(acc[1], srcLane);
  float c2 = __shfl(acc[2], srcLane);
  float c3 = __shfl(acc[3], srcLane);
  int sel = lane & 3;
  float av = sel == 0 ? c0 : sel == 1 ? c1 : sel == 2 ? c2 : c3;
  float r0 = av / ssum + bias[lane];     // z row, one float per lane
  z_out[(size_t)v*F + lane] = r0;
  unsigned short hh = f2bf_rn(r0);
  zhi[(size_t)v*F + lane] = hh;
  zlo[(size_t)v*F + lane] = f2bf_rn(r0 - bf2f(hh));
  // Student-t q
  float myq = 0.f, tot = 0.f;
  for (int k = 0; k < K; ++k){
    float d = r0 - centers[k*F + lane];
    float d2 = d*d;
    for (int o = 32; o; o >>= 1) d2 += __shfl_xor(d2, o);
    float qq = 1.f / (1.f + d2);
    if (lane == k) myq = qq;
    tot += qq;
  }
  if (lane < K) qout[(size_t)v*K + lane] = myq / tot;
}

// ---------------- A_pred = sigmoid(z z^T) via bf16-split MFMA ----------------
// block = 4 waves; wave covers 16 rows x 128 cols; grid (N/128, N/64), XCD-swizzled
__device__ __forceinline__ v8bf ldz(const unsigned short* z, int node, int k){
  return *reinterpret_cast<const v8bf*>(z + ((size_t)node << 6) + k);
}

__global__ __launch_bounds__(256) void apred_kernel(const unsigned short* __restrict__ zhi,
    const unsigned short* __restrict__ zlo, float* __restrict__ out, int N){
  __shared__ float tile[4][16][132];       // per-wave private 16x128 (+4 pad)
  // bijective XCD swizzle: consecutive swizzled ids land on the same XCD
  const int nwg = gridDim.x * gridDim.y;
  int wg = blockIdx.y * gridDim.x + blockIdx.x;
  int cpx = nwg >> 3;
  int swz = (wg & 7) * cpx + (wg >> 3);
  int by = swz / gridDim.x;
  int bx = swz - by * gridDim.x;
  const int lane = threadIdx.x & 63;
  const int wave = threadIdx.x >> 6;
  const int i0 = by*64 + wave*16;
  const int j0 = bx*128;
  const int r = lane & 15, q = lane >> 4;
  const int arow = i0 + r;
  v8bf ahi0 = ldz(zhi, arow,      q*8);
  v8bf ahi1 = ldz(zhi, arow, 32 + q*8);
  v8bf alo0 = ldz(zlo, arow,      q*8);
  v8bf alo1 = ldz(zlo, arow, 32 + q*8);
  #pragma unroll
  for (int c = 0; c < 8; ++c){
    int brow = j0 + c*16 + r;
    v8bf bhi0 = ldz(zhi, brow,      q*8);
    v8bf bhi1 = ldz(zhi, brow, 32 + q*8);
    v8bf blo0 = ldz(zlo, brow,      q*8);
    v8bf blo1 = ldz(zlo, brow, 32 + q*8);
    v4f acc = {0.f,0.f,0.f,0.f};
    acc = __builtin_amdgcn_mfma_f32_16x16x32_bf16(ahi0, bhi0, acc, 0,0,0);
    acc = __builtin_amdgcn_mfma_f32_16x16x32_bf16(ahi1, bhi1, acc, 0,0,0);
    acc = __builtin_amdgcn_mfma_f32_16x16x32_bf16(ahi0, blo0, acc, 0,0,0);
    acc = __builtin_amdgcn_mfma_f32_16x16x32_bf16(ahi1, blo1, acc, 0,0,0);
    acc = __builtin_amdgcn_mfma_f32_16x16x32_bf16(alo0, bhi0, acc, 0,0,0);
    acc = __builtin_amdgcn_mfma_f32_16x16x32_bf16(alo1, bhi1, acc, 0,0,0);
    // C/D: col = lane&15, row = q*4 + t  -> sigmoid -> LDS (wave-private, no barrier)
    #pragma unroll
    for (int t = 0; t < 4; ++t){
      float e = __expf(-acc[t]);
      tile[wave][q*4 + t][c*16 + r] = __builtin_amdgcn_rcpf(1.f + e);
    }
  }
  // store: each instr writes 2 full 512B-contiguous rows (32 lanes x float4 per row)
  #pragma unroll
  for (int t = 0; t < 8; ++t){
    int row = t*2 + (lane >> 5);
    int col = (lane & 31)*4;
    v4f vv = *reinterpret_cast<v4f*>(&tile[wave][row][col]);
    __builtin_nontemporal_store(vv, reinterpret_cast<v4f*>(out + (size_t)(i0 + row)*N + j0 + col));
  }
}

// ---------------- launch ----------------
extern "C" void kernel_launch(void* const* d_in, const int* in_sizes, int n_in,
                              void* d_out, int out_size, void* d_ws, size_t ws_size,
                              hipStream_t stream) {
  const float* x      = (const float*)d_in[0];
  const int*   ei     = (const int*)  d_in[1];
  const float* W1     = (const float*)d_in[2];
  const float* a_src1 = (const float*)d_in[3];
  const float* a_dst1 = (const float*)d_in[4];
  const float* b1     = (const float*)d_in[5];
  const float* W2     = (const float*)d_in[6];
  const float* a_src2 = (const float*)d_in[7];
  const float* a_dst2 = (const float*)d_in[8];
  const float* b2     = (const float*)d_in[9];
  const float* cent   = (const float*)d_in[10];

  const int H   = in_sizes[3];          // 128
  const int OUTF= in_sizes[7];          // 64
  const int INF = in_sizes[2] / H;      // 512
  const int N   = in_sizes[0] / INF;    // 8192
  const int E   = in_sizes[1] / 2;      // 262144
  const int K   = in_sizes[10] / OUTF;  // 16

  const int* e_src = ei;
  const int* e_dst = ei + E;

  char* wsp = (char*)d_ws;
  auto alloc = [&](size_t b)->void*{ void* p = (void*)wsp; wsp += (b + 255) & ~(size_t)255; return p; };
  int* counts   = (int*)alloc((size_t)N*4);
  int* ptr      = (int*)alloc((size_t)(N+1)*4);
  int* cursor   = (int*)alloc((size_t)N*4);
  int* csr_src  = (int*)alloc((size_t)E*4);
  float* as1    = (float*)alloc((size_t)N*4);
  float* ad1    = (float*)alloc((size_t)N*4);
  float* as2    = (float*)alloc((size_t)N*4);
  float* ad2    = (float*)alloc((size_t)N*4);
  unsigned short* zhi = (unsigned short*)alloc((size_t)N*OUTF*2);
  unsigned short* zlo = (unsigned short*)alloc((size_t)N*OUTF*2);
  unsigned short* wth = (unsigned short*)alloc((size_t)INF*H*2);
  unsigned short* wtl = (unsigned short*)alloc((size_t)INF*H*2);

  float* out_f  = (float*)d_out;
  float* z_out  = out_f;                              // [N, 64]
  float* ap_out = out_f + (size_t)N*OUTF;             // [N, N]
  float* q_out  = ap_out + (size_t)N*N;               // [N, K]
  float* h1  = ap_out;                                // scratch (dead before apred)
  float* h2  = h1 + (size_t)N*H;
  float* h2w = h2 + (size_t)N*H;

  const int wavesPerGrid = (N*64 + 255)/256;
  const int nw = INF*H;

  prep_kernel<<<(nw + N + 255)/256, 256, 0, stream>>>(W1, wth, wtl, counts, nw, N);
  hist_kernel<<<(E+255)/256, 256, 0, stream>>>(e_dst, counts, E);
  scan_kernel<<<1, 1024, 0, stream>>>(counts, ptr, cursor, N);
  scatter_kernel<<<(E+255)/256, 256, 0, stream>>>(e_src, e_dst, cursor, csr_src, E);
  gemm1_fused<<<N/32, 128, 0, stream>>>(x, wth, wtl, a_src1, a_dst1, h1, as1, ad1);
  gat_agg1<<<wavesPerGrid, 256, 0, stream>>>(h1, as1, ad1, ptr, csr_src, b1, h2, N);
  gemm2_fused<64,64,16,4,4><<<dim3(OUTF/64, N/64), 256, 0, stream>>>(h2, W2, h2w, N, OUTF, H,
                                                                     a_src2, a_dst2, as2, ad2);
  gat_agg2_fused<<<wavesPerGrid, 256, 0, stream>>>(h2w, as2, ad2, ptr, csr_src, b2, cent,
                                                   z_out, zhi, zlo, q_out, N, K);
  apred_kernel<<<dim3(N/128, N/64), 256, 0, stream>>>(zhi, zlo, ap_out, N);
}

// Round 4
// 514.910 us; speedup vs baseline: 1.0924x; 1.0259x over previous
//
#include <hip/hip_runtime.h>
#include <hip/hip_bf16.h>

typedef __bf16 v8bf __attribute__((ext_vector_type(8)));
typedef unsigned short v8us __attribute__((ext_vector_type(8)));
typedef float  v4f  __attribute__((ext_vector_type(4)));

__device__ __forceinline__ float lrelu02(float x){ return x > 0.f ? x : 0.2f*x; }

__device__ __forceinline__ unsigned short f2bf_rn(float f){
  unsigned int u = __float_as_uint(f);
  u += 0x7fffu + ((u >> 16) & 1u);
  return (unsigned short)(u >> 16);
}
__device__ __forceinline__ float bf2f(unsigned short h){
  return __uint_as_float(((unsigned int)h) << 16);
}

union BF8cast { v8us u; v8bf b; };

// ---------------- CSR build ----------------
__global__ void hist_kernel(const int* __restrict__ dst, int* counts, int E){
  int i = blockIdx.x*blockDim.x + threadIdx.x;
  if (i < E) atomicAdd(&counts[dst[i]], 1);
}

// single block, 1024 threads, n <= 8192
__global__ void scan_kernel(const int* __restrict__ counts, int* ptr, int* cursor, int n){
  __shared__ int sd[1024];
  int t = threadIdx.x;
  int base = t*8;
  int v[8]; int s = 0;
  #pragma unroll
  for (int i = 0; i < 8; ++i){ int x = (base+i < n) ? counts[base+i] : 0; v[i] = x; s += x; }
  sd[t] = s; __syncthreads();
  for (int off = 1; off < 1024; off <<= 1){
    int x = (t >= off) ? sd[t-off] : 0;
    __syncthreads();
    sd[t] += x;
    __syncthreads();
  }
  int run = sd[t] - s;
  #pragma unroll
  for (int i = 0; i < 8; ++i){
    if (base+i < n){ ptr[base+i] = run; cursor[base+i] = run; run += v[i]; }
  }
  if (t == 1023) ptr[n] = run;
}

__global__ void scatter_kernel(const int* __restrict__ src, const int* __restrict__ dst,
                               int* cursor, int* csr_src, int E){
  int i = blockIdx.x*blockDim.x + threadIdx.x;
  if (i < E){
    int p = atomicAdd(&cursor[dst[i]], 1);
    csr_src[p] = src[i];
  }
}

// ---------------- W1 split/transpose + counts zero (fused prep) ----------------
__global__ void prep_kernel(const float* __restrict__ W1,
    unsigned short* wth, unsigned short* wtl, int* counts, int nw, int n){
  int i = blockIdx.x*blockDim.x + threadIdx.x;
  if (i < nw){
    int k = i >> 7, c = i & 127;           // W1 is [512,128] row-major
    float f = W1[i];
    unsigned short h = f2bf_rn(f);
    wth[c*512 + k] = h;                     // transposed: Wt[c][k]
    wtl[c*512 + k] = f2bf_rn(f - bf2f(h));
  } else if (i < nw + n){
    counts[i - nw] = 0;
  }
}

// ---------------- GEMM1: h1 = x @ W1 via bf16-split MFMA, x split in-register,
// alpha1 (h1 @ a_src / a_dst) fused into the epilogue ----------------
// block = 128 threads (2 waves), wave covers 16 rows x 128 cols; grid = M/32
__global__ __launch_bounds__(128) void gemm1_fused(const float* __restrict__ x,
    const unsigned short* __restrict__ wth, const unsigned short* __restrict__ wtl,
    const float* __restrict__ avs, const float* __restrict__ avd,
    float* __restrict__ h1, float* __restrict__ as_out, float* __restrict__ ad_out){
  const int lane = threadIdx.x & 63;
  const int wave = threadIdx.x >> 6;
  const int i0 = blockIdx.x*32 + wave*16;
  const int r = lane & 15, q = lane >> 4;
  const float* xr = x + (size_t)(i0 + r)*512;
  v4f acc[8];
  #pragma unroll
  for (int c = 0; c < 8; ++c) acc[c] = (v4f){0.f,0.f,0.f,0.f};
  for (int kt = 0; kt < 16; ++kt){
    int k = kt*32 + q*8;
    v4f xa = *reinterpret_cast<const v4f*>(xr + k);
    v4f xb = *reinterpret_cast<const v4f*>(xr + k + 4);
    v8us ahu, alu;
    #pragma unroll
    for (int j = 0; j < 8; ++j){
      float f = (j < 4) ? xa[j] : xb[j-4];
      unsigned short hh = f2bf_rn(f);
      ahu[j] = hh;
      alu[j] = f2bf_rn(f - bf2f(hh));
    }
    BF8cast ch; ch.u = ahu;
    BF8cast cl; cl.u = alu;
    v8bf ah = ch.b, al = cl.b;
    #pragma unroll
    for (int ct = 0; ct < 8; ++ct){
      v8bf bh = *reinterpret_cast<const v8bf*>(wth + (size_t)(ct*16 + r)*512 + k);
      v8bf bl = *reinterpret_cast<const v8bf*>(wtl + (size_t)(ct*16 + r)*512 + k);
      acc[ct] = __builtin_amdgcn_mfma_f32_16x16x32_bf16(ah, bh, acc[ct], 0,0,0);
      acc[ct] = __builtin_amdgcn_mfma_f32_16x16x32_bf16(al, bh, acc[ct], 0,0,0);
      acc[ct] = __builtin_amdgcn_mfma_f32_16x16x32_bf16(ah, bl, acc[ct], 0,0,0);
    }
  }
  // C/D: col = ct*16 + (lane&15), row = i0 + q*4 + t
  #pragma unroll
  for (int ct = 0; ct < 8; ++ct)
    #pragma unroll
    for (int t = 0; t < 4; ++t)
      h1[(size_t)(i0 + q*4 + t)*128 + ct*16 + r] = acc[ct][t];
  // fused alpha: row dot a_src / a_dst. Row (q*4+t) lives across the 16 r-lanes.
  float sa[4] = {0.f,0.f,0.f,0.f}, da[4] = {0.f,0.f,0.f,0.f};
  #pragma unroll
  for (int ct = 0; ct < 8; ++ct){
    float ws = avs[ct*16 + r], wd = avd[ct*16 + r];
    #pragma unroll
    for (int t = 0; t < 4; ++t){ sa[t] += acc[ct][t]*ws; da[t] += acc[ct][t]*wd; }
  }
  #pragma unroll
  for (int off = 1; off < 16; off <<= 1){
    #pragma unroll
    for (int t = 0; t < 4; ++t){
      sa[t] += __shfl_xor(sa[t], off);
      da[t] += __shfl_xor(da[t], off);
    }
  }
  if (r == 0){
    #pragma unroll
    for (int t = 0; t < 4; ++t){
      as_out[i0 + q*4 + t] = sa[t];
      ad_out[i0 + q*4 + t] = da[t];
    }
  }
}

// ---------------- GAT layer 1: softmax + aggregate (wave per node, 2 edges/iter)
// + fused layer-2 feature transform (h2w = elu(agg)@W2) + fused alpha2 ----------------
__global__ void gat_agg1(const float* __restrict__ h, const float* __restrict__ as,
                         const float* __restrict__ ad, const int* __restrict__ ptr,
                         const int* __restrict__ csr_src, const float* __restrict__ bias,
                         const float* __restrict__ W2, const float* __restrict__ avs2,
                         const float* __restrict__ avd2,
                         float* __restrict__ h2w, float* __restrict__ as2,
                         float* __restrict__ ad2, int n){
  const int F = 128;
  int wid = (blockIdx.x*blockDim.x + threadIdx.x) >> 6;
  int lane = threadIdx.x & 63;
  if (wid >= n) return;
  const int v = wid;
  const int beg = ptr[v], end = ptr[v+1];
  const int deg = end - beg;
  const float adv = ad[v];
  const float asv = as[v];
  const float eself = lrelu02(asv + adv);
  // cached first chunk (covers deg<=64, which is ~all nodes at mean degree 32)
  int sv0 = v; float e0 = -3.4e38f;
  if (lane < deg){ sv0 = csr_src[beg + lane]; e0 = lrelu02(as[sv0] + adv); }
  float m = fmaxf(eself, e0);
  for (int j = beg + 64 + lane; j < end; j += 64)
    m = fmaxf(m, lrelu02(as[csr_src[j]] + adv));
  for (int o = 32; o; o >>= 1) m = fmaxf(m, __shfl_xor(m, o));
  float wv0 = (lane < deg) ? __expf(e0 - m) : 0.f;
  float wself = __expf(eself - m);
  float ssum = wv0 + ((lane == 0) ? wself : 0.f);
  const int half = lane >> 5, l32 = lane & 31;
  v4f acc = (v4f){0.f,0.f,0.f,0.f};
  if (half == 0){
    v4f hv = *reinterpret_cast<const v4f*>(h + (size_t)v*F + l32*4);
    acc += hv * wself;
  }
  // first chunk aggregate from register cache
  {
    int cnt = min(64, deg);
    for (int t = 0; t < cnt; t += 2){
      int idx = t + half;
      float wt = __shfl(wv0, idx);
      int   st = __shfl(sv0, idx);
      if (idx >= cnt){ wt = 0.f; st = v; }
      v4f hv = *reinterpret_cast<const v4f*>(h + (size_t)st*F + l32*4);
      acc += hv * wt;
    }
  }
  // tail chunks (deg > 64: rare)
  for (int b0 = beg + 64; b0 < end; b0 += 64){
    int j = b0 + lane;
    float wv = 0.f; int sv = v;
    if (j < end){
      sv = csr_src[j];
      wv = __expf(lrelu02(as[sv] + adv) - m);
      ssum += wv;
    }
    int cnt = min(64, end - b0);
    for (int t = 0; t < cnt; t += 2){
      int idx = t + half;
      float wt = __shfl(wv, idx);
      int   st = __shfl(sv, idx);
      if (idx >= cnt){ wt = 0.f; st = v; }
      v4f hv = *reinterpret_cast<const v4f*>(h + (size_t)st*F + l32*4);
      acc += hv * wt;
    }
  }
  for (int o = 32; o; o >>= 1) ssum += __shfl_xor(ssum, o);
  #pragma unroll
  for (int c = 0; c < 4; ++c) acc[c] += __shfl_xor(acc[c], 32);
  // ELU'd layer-1 output row: cols l32*4..+3, identical in both wave halves
  float inv = 1.f / ssum;
  v4f bv = *reinterpret_cast<const v4f*>(bias + l32*4);
  v4f rr;
  #pragma unroll
  for (int c = 0; c < 4; ++c){
    float r0 = acc[c]*inv + bv[c];
    rr[c] = r0 > 0.f ? r0 : __expf(r0) - 1.f;   // ELU
  }
  // fused layer-2 transform: lane owns output col `lane` of h2w[v] = rr_row @ W2
  // W2 is [128,64] row-major; lane-consecutive reads are coalesced, W2 L1-resident.
  float hw = 0.f;
  #pragma unroll
  for (int k = 0; k < 128; ++k){
    float rk = __shfl(rr[k & 3], k >> 2);       // broadcast row element k (lanes 0..31)
    hw += rk * W2[(size_t)k*64 + lane];
  }
  h2w[(size_t)v*64 + lane] = hw;
  // fused alpha2: dots of h2w row with a_src2 / a_dst2
  float ps = hw * avs2[lane];
  float pd = hw * avd2[lane];
  for (int o = 32; o; o >>= 1){ ps += __shfl_xor(ps, o); pd += __shfl_xor(pd, o); }
  if (lane == 0){ as2[v] = ps; ad2[v] = pd; }
}

// ---------------- GAT layer 2 + z-split + Student-t q (fused, 4 edges/iter)
// first 64 edges cached in registers from the max pass ----------------
__global__ void gat_agg2_fused(const float* __restrict__ h, const float* __restrict__ as,
                               const float* __restrict__ ad, const int* __restrict__ ptr,
                               const int* __restrict__ csr_src, const float* __restrict__ bias,
                               const float* __restrict__ centers,
                               float* __restrict__ z_out, unsigned short* __restrict__ zhi,
                               unsigned short* __restrict__ zlo, float* __restrict__ qout,
                               int n, int K){
  const int F = 64;
  int wid = (blockIdx.x*blockDim.x + threadIdx.x) >> 6;
  int lane = threadIdx.x & 63;
  if (wid >= n) return;
  const int v = wid;
  const int beg = ptr[v], end = ptr[v+1];
  const int deg = end - beg;
  const float adv = ad[v];
  const float asv = as[v];
  const float eself = lrelu02(asv + adv);
  int sv0 = v; float e0 = -3.4e38f;
  if (lane < deg){ sv0 = csr_src[beg + lane]; e0 = lrelu02(as[sv0] + adv); }
  float m = fmaxf(eself, e0);
  for (int j = beg + 64 + lane; j < end; j += 64)
    m = fmaxf(m, lrelu02(as[csr_src[j]] + adv));
  for (int o = 32; o; o >>= 1) m = fmaxf(m, __shfl_xor(m, o));
  float wv0 = (lane < deg) ? __expf(e0 - m) : 0.f;
  float wself = __expf(eself - m);
  float ssum = wv0 + ((lane == 0) ? wself : 0.f);
  const int qr = lane >> 4, l16 = lane & 15;
  v4f acc = (v4f){0.f,0.f,0.f,0.f};
  if (qr == 0){
    v4f hv = *reinterpret_cast<const v4f*>(h + (size_t)v*F + l16*4);
    acc += hv * wself;
  }
  {
    int cnt = min(64, deg);
    for (int t = 0; t < cnt; t += 4){
      int idx = t + qr;
      float wt = __shfl(wv0, idx);
      int   st = __shfl(sv0, idx);
      if (idx >= cnt){ wt = 0.f; st = v; }
      v4f hv = *reinterpret_cast<const v4f*>(h + (size_t)st*F + l16*4);
      acc += hv * wt;
    }
  }
  for (int b0 = beg + 64; b0 < end; b0 += 64){
    int j = b0 + lane;
    float wv = 0.f; int sv = v;
    if (j < end){
      sv = csr_src[j];
      wv = __expf(lrelu02(as[sv] + adv) - m);
      ssum += wv;
    }
    int cnt = min(64, end - b0);
    for (int t = 0; t < cnt; t += 4){
      int idx = t + qr;
      float wt = __shfl(wv, idx);
      int   st = __shfl(sv, idx);
      if (idx >= cnt){ wt = 0.f; st = v; }
      v4f hv = *reinterpret_cast<const v4f*>(h + (size_t)st*F + l16*4);
      acc += hv * wt;
    }
  }
  for (int o = 32; o; o >>= 1) ssum += __shfl_xor(ssum, o);
  // combine the 4 quarter-wave partials (all quarters hold cols l16*4..+3)
  #pragma unroll
  for (int c = 0; c < 4; ++c){
    acc[c] += __shfl_xor(acc[c], 16);
    acc[c] += __shfl_xor(acc[c], 32);
  }
  // redistribute: lane wants col=lane = component (lane&3) of lane (lane>>2)
  int srcLane = lane >> 2;
  float c0 = __shfl(acc[0], srcLane);
  float c1 = __shfl(acc[1], srcLane);
  float c2 = __shfl(acc[2], srcLane);
  float c3 = __shfl(acc[3], srcLane);
  int sel = lane & 3;
  float av = sel == 0 ? c0 : sel == 1 ? c1 : sel == 2 ? c2 : c3;
  float r0 = av / ssum + bias[lane];     // z row, one float per lane
  z_out[(size_t)v*F + lane] = r0;
  unsigned short hh = f2bf_rn(r0);
  zhi[(size_t)v*F + lane] = hh;
  zlo[(size_t)v*F + lane] = f2bf_rn(r0 - bf2f(hh));
  // Student-t q
  float myq = 0.f, tot = 0.f;
  for (int k = 0; k < K; ++k){
    float d = r0 - centers[k*F + lane];
    float d2 = d*d;
    for (int o = 32; o; o >>= 1) d2 += __shfl_xor(d2, o);
    float qq = 1.f / (1.f + d2);
    if (lane == k) myq = qq;
    tot += qq;
  }
  if (lane < K) qout[(size_t)v*K + lane] = myq / tot;
}

// ---------------- A_pred = sigmoid(z z^T) via bf16-split MFMA ----------------
// block = 4 waves; wave covers 16 rows x 128 cols; grid (N/128, N/64), XCD-swizzled
__device__ __forceinline__ v8bf ldz(const unsigned short* z, int node, int k){
  return *reinterpret_cast<const v8bf*>(z + ((size_t)node << 6) + k);
}

__global__ __launch_bounds__(256) void apred_kernel(const unsigned short* __restrict__ zhi,
    const unsigned short* __restrict__ zlo, float* __restrict__ out, int N){
  __shared__ float tile[4][16][132];       // per-wave private 16x128 (+4 pad)
  // bijective XCD swizzle: consecutive swizzled ids land on the same XCD
  const int nwg = gridDim.x * gridDim.y;
  int wg = blockIdx.y * gridDim.x + blockIdx.x;
  int cpx = nwg >> 3;
  int swz = (wg & 7) * cpx + (wg >> 3);
  int by = swz / gridDim.x;
  int bx = swz - by * gridDim.x;
  const int lane = threadIdx.x & 63;
  const int wave = threadIdx.x >> 6;
  const int i0 = by*64 + wave*16;
  const int j0 = bx*128;
  const int r = lane & 15, q = lane >> 4;
  const int arow = i0 + r;
  v8bf ahi0 = ldz(zhi, arow,      q*8);
  v8bf ahi1 = ldz(zhi, arow, 32 + q*8);
  v8bf alo0 = ldz(zlo, arow,      q*8);
  v8bf alo1 = ldz(zlo, arow, 32 + q*8);
  #pragma unroll
  for (int c = 0; c < 8; ++c){
    int brow = j0 + c*16 + r;
    v8bf bhi0 = ldz(zhi, brow,      q*8);
    v8bf bhi1 = ldz(zhi, brow, 32 + q*8);
    v8bf blo0 = ldz(zlo, brow,      q*8);
    v8bf blo1 = ldz(zlo, brow, 32 + q*8);
    v4f acc = {0.f,0.f,0.f,0.f};
    acc = __builtin_amdgcn_mfma_f32_16x16x32_bf16(ahi0, bhi0, acc, 0,0,0);
    acc = __builtin_amdgcn_mfma_f32_16x16x32_bf16(ahi1, bhi1, acc, 0,0,0);
    acc = __builtin_amdgcn_mfma_f32_16x16x32_bf16(ahi0, blo0, acc, 0,0,0);
    acc = __builtin_amdgcn_mfma_f32_16x16x32_bf16(ahi1, blo1, acc, 0,0,0);
    acc = __builtin_amdgcn_mfma_f32_16x16x32_bf16(alo0, bhi0, acc, 0,0,0);
    acc = __builtin_amdgcn_mfma_f32_16x16x32_bf16(alo1, bhi1, acc, 0,0,0);
    // C/D: col = lane&15, row = q*4 + t  -> sigmoid -> LDS (wave-private, no barrier)
    #pragma unroll
    for (int t = 0; t < 4; ++t){
      float e = __expf(-acc[t]);
      tile[wave][q*4 + t][c*16 + r] = __builtin_amdgcn_rcpf(1.f + e);
    }
  }
  // store: each instr writes 2 full 512B-contiguous rows (32 lanes x float4 per row)
  #pragma unroll
  for (int t = 0; t < 8; ++t){
    int row = t*2 + (lane >> 5);
    int col = (lane & 31)*4;
    v4f vv = *reinterpret_cast<v4f*>(&tile[wave][row][col]);
    __builtin_nontemporal_store(vv, reinterpret_cast<v4f*>(out + (size_t)(i0 + row)*N + j0 + col));
  }
}

// ---------------- launch ----------------
extern "C" void kernel_launch(void* const* d_in, const int* in_sizes, int n_in,
                              void* d_out, int out_size, void* d_ws, size_t ws_size,
                              hipStream_t stream) {
  const float* x      = (const float*)d_in[0];
  const int*   ei     = (const int*)  d_in[1];
  const float* W1     = (const float*)d_in[2];
  const float* a_src1 = (const float*)d_in[3];
  const float* a_dst1 = (const float*)d_in[4];
  const float* b1     = (const float*)d_in[5];
  const float* W2     = (const float*)d_in[6];
  const float* a_src2 = (const float*)d_in[7];
  const float* a_dst2 = (const float*)d_in[8];
  const float* b2     = (const float*)d_in[9];
  const float* cent   = (const float*)d_in[10];

  const int H   = in_sizes[3];          // 128
  const int OUTF= in_sizes[7];          // 64
  const int INF = in_sizes[2] / H;      // 512
  const int N   = in_sizes[0] / INF;    // 8192
  const int E   = in_sizes[1] / 2;      // 262144
  const int K   = in_sizes[10] / OUTF;  // 16

  const int* e_src = ei;
  const int* e_dst = ei + E;

  char* wsp = (char*)d_ws;
  auto alloc = [&](size_t b)->void*{ void* p = (void*)wsp; wsp += (b + 255) & ~(size_t)255; return p; };
  int* counts   = (int*)alloc((size_t)N*4);
  int* ptr      = (int*)alloc((size_t)(N+1)*4);
  int* cursor   = (int*)alloc((size_t)N*4);
  int* csr_src  = (int*)alloc((size_t)E*4);
  float* as1    = (float*)alloc((size_t)N*4);
  float* ad1    = (float*)alloc((size_t)N*4);
  float* as2    = (float*)alloc((size_t)N*4);
  float* ad2    = (float*)alloc((size_t)N*4);
  unsigned short* zhi = (unsigned short*)alloc((size_t)N*OUTF*2);
  unsigned short* zlo = (unsigned short*)alloc((size_t)N*OUTF*2);
  unsigned short* wth = (unsigned short*)alloc((size_t)INF*H*2);
  unsigned short* wtl = (unsigned short*)alloc((size_t)INF*H*2);

  float* out_f  = (float*)d_out;
  float* z_out  = out_f;                              // [N, 64]
  float* ap_out = out_f + (size_t)N*OUTF;             // [N, N]
  float* q_out  = ap_out + (size_t)N*N;               // [N, K]
  float* h1  = ap_out;                                // scratch (dead before apred)
  float* h2w = h1 + (size_t)N*H;                      // [N, 64] scratch

  const int wavesPerGrid = (N*64 + 255)/256;
  const int nw = INF*H;

  prep_kernel<<<(nw + N + 255)/256, 256, 0, stream>>>(W1, wth, wtl, counts, nw, N);
  hist_kernel<<<(E+255)/256, 256, 0, stream>>>(e_dst, counts, E);
  scan_kernel<<<1, 1024, 0, stream>>>(counts, ptr, cursor, N);
  scatter_kernel<<<(E+255)/256, 256, 0, stream>>>(e_src, e_dst, cursor, csr_src, E);
  gemm1_fused<<<N/32, 128, 0, stream>>>(x, wth, wtl, a_src1, a_dst1, h1, as1, ad1);
  gat_agg1<<<wavesPerGrid, 256, 0, stream>>>(h1, as1, ad1, ptr, csr_src, b1,
                                             W2, a_src2, a_dst2, h2w, as2, ad2, N);
  gat_agg2_fused<<<wavesPerGrid, 256, 0, stream>>>(h2w, as2, ad2, ptr, csr_src, b2, cent,
                                                   z_out, zhi, zlo, q_out, N, K);
  apred_kernel<<<dim3(N/128, N/64), 256, 0, stream>>>(zhi, zlo, ap_out, N);
}

// Round 5
// 514.560 us; speedup vs baseline: 1.0931x; 1.0007x over previous
//
#include <hip/hip_runtime.h>
#include <hip/hip_bf16.h>

typedef __bf16 v8bf __attribute__((ext_vector_type(8)));
typedef unsigned short v8us __attribute__((ext_vector_type(8)));
typedef float  v4f  __attribute__((ext_vector_type(4)));

__device__ __forceinline__ float lrelu02(float x){ return x > 0.f ? x : 0.2f*x; }

__device__ __forceinline__ unsigned short f2bf_rn(float f){
  unsigned int u = __float_as_uint(f);
  u += 0x7fffu + ((u >> 16) & 1u);
  return (unsigned short)(u >> 16);
}
__device__ __forceinline__ float bf2f(unsigned short h){
  return __uint_as_float(((unsigned int)h) << 16);
}

union BF8cast { v8us u; v8bf b; };

// ---------------- CSR build ----------------
__global__ void hist_kernel(const int* __restrict__ dst, int* counts, int E){
  int i = blockIdx.x*blockDim.x + threadIdx.x;
  if (i < E) atomicAdd(&counts[dst[i]], 1);
}

// single block, 1024 threads, n <= 8192
__global__ void scan_kernel(const int* __restrict__ counts, int* ptr, int* cursor, int n){
  __shared__ int sd[1024];
  int t = threadIdx.x;
  int base = t*8;
  int v[8]; int s = 0;
  #pragma unroll
  for (int i = 0; i < 8; ++i){ int x = (base+i < n) ? counts[base+i] : 0; v[i] = x; s += x; }
  sd[t] = s; __syncthreads();
  for (int off = 1; off < 1024; off <<= 1){
    int x = (t >= off) ? sd[t-off] : 0;
    __syncthreads();
    sd[t] += x;
    __syncthreads();
  }
  int run = sd[t] - s;
  #pragma unroll
  for (int i = 0; i < 8; ++i){
    if (base+i < n){ ptr[base+i] = run; cursor[base+i] = run; run += v[i]; }
  }
  if (t == 1023) ptr[n] = run;
}

__global__ void scatter_kernel(const int* __restrict__ src, const int* __restrict__ dst,
                               int* cursor, int* csr_src, int E){
  int i = blockIdx.x*blockDim.x + threadIdx.x;
  if (i < E){
    int p = atomicAdd(&cursor[dst[i]], 1);
    csr_src[p] = src[i];
  }
}

// ---------------- W1 split/transpose + counts zero (fused prep) ----------------
__global__ void prep_kernel(const float* __restrict__ W1,
    unsigned short* wth, unsigned short* wtl, int* counts, int nw, int n){
  int i = blockIdx.x*blockDim.x + threadIdx.x;
  if (i < nw){
    int k = i >> 7, c = i & 127;           // W1 is [512,128] row-major
    float f = W1[i];
    unsigned short h = f2bf_rn(f);
    wth[c*512 + k] = h;                     // transposed: Wt[c][k]
    wtl[c*512 + k] = f2bf_rn(f - bf2f(h));
  } else if (i < nw + n){
    counts[i - nw] = 0;
  }
}

// ---------------- GEMM1: h1 = x @ W1 via bf16-split MFMA, x split in-register,
// alpha1 (h1 @ a_src / a_dst) fused into the epilogue ----------------
// block = 128 threads (2 waves), wave covers 16 rows x 128 cols; grid = M/32
__global__ __launch_bounds__(128) void gemm1_fused(const float* __restrict__ x,
    const unsigned short* __restrict__ wth, const unsigned short* __restrict__ wtl,
    const float* __restrict__ avs, const float* __restrict__ avd,
    float* __restrict__ h1, float* __restrict__ as_out, float* __restrict__ ad_out){
  const int lane = threadIdx.x & 63;
  const int wave = threadIdx.x >> 6;
  const int i0 = blockIdx.x*32 + wave*16;
  const int r = lane & 15, q = lane >> 4;
  const float* xr = x + (size_t)(i0 + r)*512;
  v4f acc[8];
  #pragma unroll
  for (int c = 0; c < 8; ++c) acc[c] = (v4f){0.f,0.f,0.f,0.f};
  for (int kt = 0; kt < 16; ++kt){
    int k = kt*32 + q*8;
    v4f xa = *reinterpret_cast<const v4f*>(xr + k);
    v4f xb = *reinterpret_cast<const v4f*>(xr + k + 4);
    v8us ahu, alu;
    #pragma unroll
    for (int j = 0; j < 8; ++j){
      float f = (j < 4) ? xa[j] : xb[j-4];
      unsigned short hh = f2bf_rn(f);
      ahu[j] = hh;
      alu[j] = f2bf_rn(f - bf2f(hh));
    }
    BF8cast ch; ch.u = ahu;
    BF8cast cl; cl.u = alu;
    v8bf ah = ch.b, al = cl.b;
    #pragma unroll
    for (int ct = 0; ct < 8; ++ct){
      v8bf bh = *reinterpret_cast<const v8bf*>(wth + (size_t)(ct*16 + r)*512 + k);
      v8bf bl = *reinterpret_cast<const v8bf*>(wtl + (size_t)(ct*16 + r)*512 + k);
      acc[ct] = __builtin_amdgcn_mfma_f32_16x16x32_bf16(ah, bh, acc[ct], 0,0,0);
      acc[ct] = __builtin_amdgcn_mfma_f32_16x16x32_bf16(al, bh, acc[ct], 0,0,0);
      acc[ct] = __builtin_amdgcn_mfma_f32_16x16x32_bf16(ah, bl, acc[ct], 0,0,0);
    }
  }
  // C/D: col = ct*16 + (lane&15), row = i0 + q*4 + t
  #pragma unroll
  for (int ct = 0; ct < 8; ++ct)
    #pragma unroll
    for (int t = 0; t < 4; ++t)
      h1[(size_t)(i0 + q*4 + t)*128 + ct*16 + r] = acc[ct][t];
  // fused alpha: row dot a_src / a_dst. Row (q*4+t) lives across the 16 r-lanes.
  float sa[4] = {0.f,0.f,0.f,0.f}, da[4] = {0.f,0.f,0.f,0.f};
  #pragma unroll
  for (int ct = 0; ct < 8; ++ct){
    float ws = avs[ct*16 + r], wd = avd[ct*16 + r];
    #pragma unroll
    for (int t = 0; t < 4; ++t){ sa[t] += acc[ct][t]*ws; da[t] += acc[ct][t]*wd; }
  }
  #pragma unroll
  for (int off = 1; off < 16; off <<= 1){
    #pragma unroll
    for (int t = 0; t < 4; ++t){
      sa[t] += __shfl_xor(sa[t], off);
      da[t] += __shfl_xor(da[t], off);
    }
  }
  if (r == 0){
    #pragma unroll
    for (int t = 0; t < 4; ++t){
      as_out[i0 + q*4 + t] = sa[t];
      ad_out[i0 + q*4 + t] = da[t];
    }
  }
}

// ---------------- GAT layer 1: softmax + aggregate (wave per node, 4 edges/iter,
// quarter-wave per edge, 8 floats per lane) + fused layer-2 transform + alpha2 ----------------
__global__ void gat_agg1(const float* __restrict__ h, const float* __restrict__ as,
                         const float* __restrict__ ad, const int* __restrict__ ptr,
                         const int* __restrict__ csr_src, const float* __restrict__ bias,
                         const float* __restrict__ W2, const float* __restrict__ avs2,
                         const float* __restrict__ avd2,
                         float* __restrict__ h2w, float* __restrict__ as2,
                         float* __restrict__ ad2, int n){
  const int F = 128;
  int wid = (blockIdx.x*blockDim.x + threadIdx.x) >> 6;
  int lane = threadIdx.x & 63;
  if (wid >= n) return;
  const int v = wid;
  const int beg = ptr[v], end = ptr[v+1];
  const int deg = end - beg;
  const float adv = ad[v];
  const float asv = as[v];
  const float eself = lrelu02(asv + adv);
  // cached first chunk (covers deg<=64, which is ~all nodes at mean degree 32)
  int sv0 = v; float e0 = -3.4e38f;
  if (lane < deg){ sv0 = csr_src[beg + lane]; e0 = lrelu02(as[sv0] + adv); }
  float m = fmaxf(eself, e0);
  for (int j = beg + 64 + lane; j < end; j += 64)
    m = fmaxf(m, lrelu02(as[csr_src[j]] + adv));
  for (int o = 32; o; o >>= 1) m = fmaxf(m, __shfl_xor(m, o));
  float wv0 = (lane < deg) ? __expf(e0 - m) : 0.f;
  float wself = __expf(eself - m);
  float ssum = wv0 + ((lane == 0) ? wself : 0.f);
  const int qr = lane >> 4, l16 = lane & 15;
  // lane owns cols [l16*8, l16*8+8) as two v4f; 4 quarter-wave partials
  v4f acc0 = (v4f){0.f,0.f,0.f,0.f}, acc1 = (v4f){0.f,0.f,0.f,0.f};
  if (qr == 0){
    const float* hp = h + (size_t)v*F + l16*8;
    acc0 += *reinterpret_cast<const v4f*>(hp) * wself;
    acc1 += *reinterpret_cast<const v4f*>(hp + 4) * wself;
  }
  // first chunk aggregate from register cache: 4 edges/iter
  {
    int cnt = min(64, deg);
    for (int t = 0; t < cnt; t += 4){
      int idx = t + qr;
      float wt = __shfl(wv0, idx);
      int   st = __shfl(sv0, idx);
      if (idx >= cnt){ wt = 0.f; st = v; }
      const float* hp = h + (size_t)st*F + l16*8;
      acc0 += *reinterpret_cast<const v4f*>(hp) * wt;
      acc1 += *reinterpret_cast<const v4f*>(hp + 4) * wt;
    }
  }
  // tail chunks (deg > 64: rare)
  for (int b0 = beg + 64; b0 < end; b0 += 64){
    int j = b0 + lane;
    float wv = 0.f; int sv = v;
    if (j < end){
      sv = csr_src[j];
      wv = __expf(lrelu02(as[sv] + adv) - m);
      ssum += wv;
    }
    int cnt = min(64, end - b0);
    for (int t = 0; t < cnt; t += 4){
      int idx = t + qr;
      float wt = __shfl(wv, idx);
      int   st = __shfl(sv, idx);
      if (idx >= cnt){ wt = 0.f; st = v; }
      const float* hp = h + (size_t)st*F + l16*8;
      acc0 += *reinterpret_cast<const v4f*>(hp) * wt;
      acc1 += *reinterpret_cast<const v4f*>(hp + 4) * wt;
    }
  }
  for (int o = 32; o; o >>= 1) ssum += __shfl_xor(ssum, o);
  // combine the 4 quarter partials (each quarter's 16 lanes cover all 128 cols)
  #pragma unroll
  for (int c = 0; c < 4; ++c){
    acc0[c] += __shfl_xor(acc0[c], 16); acc0[c] += __shfl_xor(acc0[c], 32);
    acc1[c] += __shfl_xor(acc1[c], 16); acc1[c] += __shfl_xor(acc1[c], 32);
  }
  // ELU'd layer-1 output row: lane holds cols l16*8..+7 (duplicated across quarters)
  float inv = 1.f / ssum;
  v4f bv0 = *reinterpret_cast<const v4f*>(bias + l16*8);
  v4f bv1 = *reinterpret_cast<const v4f*>(bias + l16*8 + 4);
  float rr8[8];
  #pragma unroll
  for (int c = 0; c < 4; ++c){
    float r0 = acc0[c]*inv + bv0[c];
    rr8[c] = r0 > 0.f ? r0 : __expf(r0) - 1.f;   // ELU
    float r1 = acc1[c]*inv + bv1[c];
    rr8[4+c] = r1 > 0.f ? r1 : __expf(r1) - 1.f;
  }
  // fused layer-2 transform: lane owns output col `lane` of h2w[v] = rr_row @ W2
  // W2 is [128,64] row-major; lane-consecutive reads are coalesced, W2 L1-resident.
  float hw = 0.f;
  #pragma unroll
  for (int k = 0; k < 128; ++k){
    float rk = __shfl(rr8[k & 7], k >> 3);       // broadcast row element k (lanes 0..15)
    hw += rk * W2[(size_t)k*64 + lane];
  }
  h2w[(size_t)v*64 + lane] = hw;
  // fused alpha2: dots of h2w row with a_src2 / a_dst2
  float ps = hw * avs2[lane];
  float pd = hw * avd2[lane];
  for (int o = 32; o; o >>= 1){ ps += __shfl_xor(ps, o); pd += __shfl_xor(pd, o); }
  if (lane == 0){ as2[v] = ps; ad2[v] = pd; }
}

// ---------------- GAT layer 2 + z-split + Student-t q (8 edges/iter,
// 8-lane group per edge, 8 floats per lane) ----------------
__global__ void gat_agg2_fused(const float* __restrict__ h, const float* __restrict__ as,
                               const float* __restrict__ ad, const int* __restrict__ ptr,
                               const int* __restrict__ csr_src, const float* __restrict__ bias,
                               const float* __restrict__ centers,
                               float* __restrict__ z_out, unsigned short* __restrict__ zhi,
                               unsigned short* __restrict__ zlo, float* __restrict__ qout,
                               int n, int K){
  const int F = 64;
  int wid = (blockIdx.x*blockDim.x + threadIdx.x) >> 6;
  int lane = threadIdx.x & 63;
  if (wid >= n) return;
  const int v = wid;
  const int beg = ptr[v], end = ptr[v+1];
  const int deg = end - beg;
  const float adv = ad[v];
  const float asv = as[v];
  const float eself = lrelu02(asv + adv);
  int sv0 = v; float e0 = -3.4e38f;
  if (lane < deg){ sv0 = csr_src[beg + lane]; e0 = lrelu02(as[sv0] + adv); }
  float m = fmaxf(eself, e0);
  for (int j = beg + 64 + lane; j < end; j += 64)
    m = fmaxf(m, lrelu02(as[csr_src[j]] + adv));
  for (int o = 32; o; o >>= 1) m = fmaxf(m, __shfl_xor(m, o));
  float wv0 = (lane < deg) ? __expf(e0 - m) : 0.f;
  float wself = __expf(eself - m);
  float ssum = wv0 + ((lane == 0) ? wself : 0.f);
  const int oct = lane >> 3, l8 = lane & 7;
  // lane owns cols [l8*8, l8*8+8) as two v4f; 8 octet partials
  v4f acc0 = (v4f){0.f,0.f,0.f,0.f}, acc1 = (v4f){0.f,0.f,0.f,0.f};
  if (oct == 0){
    const float* hp = h + (size_t)v*F + l8*8;
    acc0 += *reinterpret_cast<const v4f*>(hp) * wself;
    acc1 += *reinterpret_cast<const v4f*>(hp + 4) * wself;
  }
  {
    int cnt = min(64, deg);
    for (int t = 0; t < cnt; t += 8){
      int idx = t + oct;
      float wt = __shfl(wv0, idx);
      int   st = __shfl(sv0, idx);
      if (idx >= cnt){ wt = 0.f; st = v; }
      const float* hp = h + (size_t)st*F + l8*8;
      acc0 += *reinterpret_cast<const v4f*>(hp) * wt;
      acc1 += *reinterpret_cast<const v4f*>(hp + 4) * wt;
    }
  }
  for (int b0 = beg + 64; b0 < end; b0 += 64){
    int j = b0 + lane;
    float wv = 0.f; int sv = v;
    if (j < end){
      sv = csr_src[j];
      wv = __expf(lrelu02(as[sv] + adv) - m);
      ssum += wv;
    }
    int cnt = min(64, end - b0);
    for (int t = 0; t < cnt; t += 8){
      int idx = t + oct;
      float wt = __shfl(wv, idx);
      int   st = __shfl(sv, idx);
      if (idx >= cnt){ wt = 0.f; st = v; }
      const float* hp = h + (size_t)st*F + l8*8;
      acc0 += *reinterpret_cast<const v4f*>(hp) * wt;
      acc1 += *reinterpret_cast<const v4f*>(hp + 4) * wt;
    }
  }
  for (int o = 32; o; o >>= 1) ssum += __shfl_xor(ssum, o);
  // combine the 8 octet partials (each octet's 8 lanes cover all 64 cols)
  #pragma unroll
  for (int c = 0; c < 4; ++c){
    acc0[c] += __shfl_xor(acc0[c], 8); acc0[c] += __shfl_xor(acc0[c], 16); acc0[c] += __shfl_xor(acc0[c], 32);
    acc1[c] += __shfl_xor(acc1[c], 8); acc1[c] += __shfl_xor(acc1[c], 16); acc1[c] += __shfl_xor(acc1[c], 32);
  }
  // redistribute: lane wants col=lane = component (lane&7) of lane (lane>>3)
  int srcLane = lane >> 3;
  float t0 = __shfl(acc0[0], srcLane), t1 = __shfl(acc0[1], srcLane);
  float t2 = __shfl(acc0[2], srcLane), t3 = __shfl(acc0[3], srcLane);
  float t4 = __shfl(acc1[0], srcLane), t5 = __shfl(acc1[1], srcLane);
  float t6 = __shfl(acc1[2], srcLane), t7 = __shfl(acc1[3], srcLane);
  int sel = lane & 7;
  float lo = sel < 2 ? (sel == 0 ? t0 : t1) : (sel == 2 ? t2 : t3);
  float hi = sel < 6 ? (sel == 4 ? t4 : t5) : (sel == 6 ? t6 : t7);
  float av = sel < 4 ? lo : hi;
  float r0 = av / ssum + bias[lane];     // z row, one float per lane
  z_out[(size_t)v*F + lane] = r0;
  unsigned short hh = f2bf_rn(r0);
  zhi[(size_t)v*F + lane] = hh;
  zlo[(size_t)v*F + lane] = f2bf_rn(r0 - bf2f(hh));
  // Student-t q
  float myq = 0.f, tot = 0.f;
  for (int k = 0; k < K; ++k){
    float d = r0 - centers[k*F + lane];
    float d2 = d*d;
    for (int o = 32; o; o >>= 1) d2 += __shfl_xor(d2, o);
    float qq = 1.f / (1.f + d2);
    if (lane == k) myq = qq;
    tot += qq;
  }
  if (lane < K) qout[(size_t)v*K + lane] = myq / tot;
}

// ---------------- A_pred = sigmoid(z z^T) via bf16-split MFMA ----------------
// block = 4 waves; wave covers 16 rows x 128 cols; grid (N/128, N/64), XCD-swizzled
__device__ __forceinline__ v8bf ldz(const unsigned short* z, int node, int k){
  return *reinterpret_cast<const v8bf*>(z + ((size_t)node << 6) + k);
}

__global__ __launch_bounds__(256) void apred_kernel(const unsigned short* __restrict__ zhi,
    const unsigned short* __restrict__ zlo, float* __restrict__ out, int N){
  __shared__ float tile[4][16][132];       // per-wave private 16x128 (+4 pad)
  // bijective XCD swizzle: consecutive swizzled ids land on the same XCD
  const int nwg = gridDim.x * gridDim.y;
  int wg = blockIdx.y * gridDim.x + blockIdx.x;
  int cpx = nwg >> 3;
  int swz = (wg & 7) * cpx + (wg >> 3);
  int by = swz / gridDim.x;
  int bx = swz - by * gridDim.x;
  const int lane = threadIdx.x & 63;
  const int wave = threadIdx.x >> 6;
  const int i0 = by*64 + wave*16;
  const int j0 = bx*128;
  const int r = lane & 15, q = lane >> 4;
  const int arow = i0 + r;
  v8bf ahi0 = ldz(zhi, arow,      q*8);
  v8bf ahi1 = ldz(zhi, arow, 32 + q*8);
  v8bf alo0 = ldz(zlo, arow,      q*8);
  v8bf alo1 = ldz(zlo, arow, 32 + q*8);
  #pragma unroll
  for (int c = 0; c < 8; ++c){
    int brow = j0 + c*16 + r;
    v8bf bhi0 = ldz(zhi, brow,      q*8);
    v8bf bhi1 = ldz(zhi, brow, 32 + q*8);
    v8bf blo0 = ldz(zlo, brow,      q*8);
    v8bf blo1 = ldz(zlo, brow, 32 + q*8);
    v4f acc = {0.f,0.f,0.f,0.f};
    acc = __builtin_amdgcn_mfma_f32_16x16x32_bf16(ahi0, bhi0, acc, 0,0,0);
    acc = __builtin_amdgcn_mfma_f32_16x16x32_bf16(ahi1, bhi1, acc, 0,0,0);
    acc = __builtin_amdgcn_mfma_f32_16x16x32_bf16(ahi0, blo0, acc, 0,0,0);
    acc = __builtin_amdgcn_mfma_f32_16x16x32_bf16(ahi1, blo1, acc, 0,0,0);
    acc = __builtin_amdgcn_mfma_f32_16x16x32_bf16(alo0, bhi0, acc, 0,0,0);
    acc = __builtin_amdgcn_mfma_f32_16x16x32_bf16(alo1, bhi1, acc, 0,0,0);
    // C/D: col = lane&15, row = q*4 + t  -> sigmoid -> LDS (wave-private, no barrier)
    #pragma unroll
    for (int t = 0; t < 4; ++t){
      float e = __expf(-acc[t]);
      tile[wave][q*4 + t][c*16 + r] = __builtin_amdgcn_rcpf(1.f + e);
    }
  }
  // store: each instr writes 2 full 512B-contiguous rows (32 lanes x float4 per row)
  #pragma unroll
  for (int t = 0; t < 8; ++t){
    int row = t*2 + (lane >> 5);
    int col = (lane & 31)*4;
    v4f vv = *reinterpret_cast<v4f*>(&tile[wave][row][col]);
    __builtin_nontemporal_store(vv, reinterpret_cast<v4f*>(out + (size_t)(i0 + row)*N + j0 + col));
  }
}

// ---------------- launch ----------------
extern "C" void kernel_launch(void* const* d_in, const int* in_sizes, int n_in,
                              void* d_out, int out_size, void* d_ws, size_t ws_size,
                              hipStream_t stream) {
  const float* x      = (const float*)d_in[0];
  const int*   ei     = (const int*)  d_in[1];
  const float* W1     = (const float*)d_in[2];
  const float* a_src1 = (const float*)d_in[3];
  const float* a_dst1 = (const float*)d_in[4];
  const float* b1     = (const float*)d_in[5];
  const float* W2     = (const float*)d_in[6];
  const float* a_src2 = (const float*)d_in[7];
  const float* a_dst2 = (const float*)d_in[8];
  const float* b2     = (const float*)d_in[9];
  const float* cent   = (const float*)d_in[10];

  const int H   = in_sizes[3];          // 128
  const int OUTF= in_sizes[7];          // 64
  const int INF = in_sizes[2] / H;      // 512
  const int N   = in_sizes[0] / INF;    // 8192
  const int E   = in_sizes[1] / 2;      // 262144
  const int K   = in_sizes[10] / OUTF;  // 16

  const int* e_src = ei;
  const int* e_dst = ei + E;

  char* wsp = (char*)d_ws;
  auto alloc = [&](size_t b)->void*{ void* p = (void*)wsp; wsp += (b + 255) & ~(size_t)255; return p; };
  int* counts   = (int*)alloc((size_t)N*4);
  int* ptr      = (int*)alloc((size_t)(N+1)*4);
  int* cursor   = (int*)alloc((size_t)N*4);
  int* csr_src  = (int*)alloc((size_t)E*4);
  float* as1    = (float*)alloc((size_t)N*4);
  float* ad1    = (float*)alloc((size_t)N*4);
  float* as2    = (float*)alloc((size_t)N*4);
  float* ad2    = (float*)alloc((size_t)N*4);
  unsigned short* zhi = (unsigned short*)alloc((size_t)N*OUTF*2);
  unsigned short* zlo = (unsigned short*)alloc((size_t)N*OUTF*2);
  unsigned short* wth = (unsigned short*)alloc((size_t)INF*H*2);
  unsigned short* wtl = (unsigned short*)alloc((size_t)INF*H*2);

  float* out_f  = (float*)d_out;
  float* z_out  = out_f;                              // [N, 64]
  float* ap_out = out_f + (size_t)N*OUTF;             // [N, N]
  float* q_out  = ap_out + (size_t)N*N;               // [N, K]
  float* h1  = ap_out;                                // scratch (dead before apred)
  float* h2w = h1 + (size_t)N*H;                      // [N, 64] scratch

  const int wavesPerGrid = (N*64 + 255)/256;
  const int nw = INF*H;

  prep_kernel<<<(nw + N + 255)/256, 256, 0, stream>>>(W1, wth, wtl, counts, nw, N);
  hist_kernel<<<(E+255)/256, 256, 0, stream>>>(e_dst, counts, E);
  scan_kernel<<<1, 1024, 0, stream>>>(counts, ptr, cursor, N);
  scatter_kernel<<<(E+255)/256, 256, 0, stream>>>(e_src, e_dst, cursor, csr_src, E);
  gemm1_fused<<<N/32, 128, 0, stream>>>(x, wth, wtl, a_src1, a_dst1, h1, as1, ad1);
  gat_agg1<<<wavesPerGrid, 256, 0, stream>>>(h1, as1, ad1, ptr, csr_src, b1,
                                             W2, a_src2, a_dst2, h2w, as2, ad2, N);
  gat_agg2_fused<<<wavesPerGrid, 256, 0, stream>>>(h2w, as2, ad2, ptr, csr_src, b2, cent,
                                                   z_out, zhi, zlo, q_out, N, K);
  apred_kernel<<<dim3(N/128, N/64), 256, 0, stream>>>(zhi, zlo, ap_out, N);
}